// Round 8
// baseline (260.179 us; speedup 1.0000x reference)
//
#include <hip/hip_runtime.h>
#include <hip/hip_bf16.h>

// Dims fixed by the reference
#define BB 8
#define NN 2048
#define DF 256
#define HH 64

using bf16x8 = __attribute__((ext_vector_type(8))) short;
using f32x4  = __attribute__((ext_vector_type(4))) float;
typedef unsigned short u16;

static __device__ __forceinline__ short bf_hi_bits(float v, float* hi_f) {
    __hip_bfloat16 h = __float2bfloat16(v);
    *hi_f = __bfloat162float(h);
    return __builtin_bit_cast(short, h);
}

static __device__ __forceinline__ float bfbits2f(u16 v) {
    unsigned int x = ((unsigned int)v) << 16;
    return __builtin_bit_cast(float, x);
}

// ---------------------------------------------------------------------------
// Kernel 0: pre-split W into MFMA B-fragment order, split bf16 (hi,lo).
// Layout: [kc(8)][ct(8)][hi 512 | lo 512] u16. Wsp aliases pi head (rows
// 0-15 of b0's pi): wprep writes, qk reads, later kernels overwrite.
// ---------------------------------------------------------------------------
__global__ __launch_bounds__(64) void wprep_kernel(
    const float* __restrict__ Wq, const float* __restrict__ Wk,
    u16* __restrict__ Wsp)
{
    const int fid  = blockIdx.x;          // kc*8 + ct
    const int kc   = fid >> 3, ct = fid & 7;
    const int lane = threadIdx.x;
    const float* W = (ct < 4) ? Wq : Wk;
    const int col  = (ct & 3) * 16 + (lane & 15);
    const int krow = kc * 32 + (lane >> 4) * 8;
    bf16x8 hv, lv;
#pragma unroll
    for (int j = 0; j < 8; ++j) {
        float w = W[(size_t)(krow + j) * HH + col];
        float hf, d;
        hv[j] = bf_hi_bits(w, &hf);
        lv[j] = bf_hi_bits(w - hf, &d);
    }
    u16* dst = Wsp + (size_t)fid * 1024 + lane * 8;
    *(bf16x8*)dst         = hv;
    *(bf16x8*)(dst + 512) = lv;
}

// ---------------------------------------------------------------------------
// Kernel 1: Q/K projection (proven r7 version, unchanged). LDS-staged Wsp,
// double-buffered kc chunks, 256 blocks x 256 thr.
// ---------------------------------------------------------------------------
__global__ __launch_bounds__(256) void qk_mfma_kernel(
    const float* __restrict__ f, const float* __restrict__ log_eps,
    const float* __restrict__ Wq, const float* __restrict__ Wk,
    const u16* __restrict__ Wsp,
    __hip_bfloat16* __restrict__ Qs, __hip_bfloat16* __restrict__ Ks)
{
    __shared__ __align__(16) u16 wbuf[2][8192];   // 2 x 16 KB kc-chunks

    const int tid  = threadIdx.x;
    const int wave = tid >> 6;
    const int lane = tid & 63;
    const int l15  = lane & 15, quad = lane >> 4;
    const int row0 = blockIdx.x * 64 + wave * 16;
    const int b    = (blockIdx.x * 64) >> 11;

    f32x4 acc[8] = {};
    const float* frow = f + (size_t)(row0 + l15) * DF + quad * 8;

    {
        const uint4* src = (const uint4*)(Wsp + tid * 32);
        uint4* dst = (uint4*)&wbuf[0][tid * 32];
#pragma unroll
        for (int i = 0; i < 4; ++i) dst[i] = src[i];
    }
    float4 a0 = *(const float4*)(frow);
    float4 a1 = *(const float4*)(frow + 4);
    __syncthreads();

    for (int kc = 0; kc < 8; ++kc) {
        const int cur = kc & 1;
        uint4 w0, w1, w2, w3;
        float4 na0, na1;
        if (kc < 7) {
            const uint4* src =
                (const uint4*)(Wsp + (size_t)(kc + 1) * 8192 + tid * 32);
            w0 = src[0]; w1 = src[1]; w2 = src[2]; w3 = src[3];
            na0 = *(const float4*)(frow + (kc + 1) * 32);
            na1 = *(const float4*)(frow + (kc + 1) * 32 + 4);
        }
        bf16x8 ah, al;
#pragma unroll
        for (int e = 0; e < 4; ++e) {
            float hf, d;
            float v0 = (&a0.x)[e], v1 = (&a1.x)[e];
            ah[e]     = bf_hi_bits(v0, &hf);
            al[e]     = bf_hi_bits(v0 - hf, &d);
            ah[e + 4] = bf_hi_bits(v1, &hf);
            al[e + 4] = bf_hi_bits(v1 - hf, &d);
        }
#pragma unroll
        for (int ct = 0; ct < 8; ++ct) {
            bf16x8 bh = *(const bf16x8*)&wbuf[cur][ct * 1024 + lane * 8];
            bf16x8 bl = *(const bf16x8*)&wbuf[cur][ct * 1024 + 512 + lane * 8];
            acc[ct] = __builtin_amdgcn_mfma_f32_16x16x32_bf16(ah, bh, acc[ct], 0, 0, 0);
            acc[ct] = __builtin_amdgcn_mfma_f32_16x16x32_bf16(ah, bl, acc[ct], 0, 0, 0);
            acc[ct] = __builtin_amdgcn_mfma_f32_16x16x32_bf16(al, bh, acc[ct], 0, 0, 0);
        }
        if (kc < 7) {
            uint4* dst = (uint4*)&wbuf[cur ^ 1][tid * 32];
            dst[0] = w0; dst[1] = w1; dst[2] = w2; dst[3] = w3;
            a0 = na0; a1 = na1;
        }
        __syncthreads();
    }

    const float le = log_eps[b];
#pragma unroll
    for (int ct = 0; ct < 8; ++ct) {
        const int h = (ct & 3) * 16 + l15;
        const float wlast = (ct < 4 ? Wq : Wk)[DF * HH + h];
        __hip_bfloat16* out = (ct < 4) ? Qs : Ks;
        const float sc = (ct < 4) ? 0.125f : 1.0f;
#pragma unroll
        for (int r = 0; r < 4; ++r) {
            int bn = row0 + quad * 4 + r;
            float v = (acc[ct][r] + le * wlast) * sc;
            __hip_bfloat16 hi = __float2bfloat16(v);
            __hip_bfloat16 lo = __float2bfloat16(v - __bfloat162float(hi));
            out[(size_t)bn * 128 + h]      = hi;
            out[(size_t)bn * 128 + 64 + h] = lo;
        }
    }
}

// common fragment-load/MFMA macros
#define LOADQF(AH, AL, ROW0)                                                   \
    {                                                                          \
        const u16* qr = Qb + (size_t)((ROW0) + l15) * 128;                     \
        _Pragma("unroll")                                                      \
        for (int ks = 0; ks < 2; ++ks) {                                       \
            int k0 = ks * 32 + quad * 8;                                       \
            AH[ks] = *(const bf16x8*)(qr + k0);                                \
            AL[ks] = *(const bf16x8*)(qr + 64 + k0);                           \
        }                                                                      \
    }

// ---------------------------------------------------------------------------
// Kernel 2: exact column sums + y. Grid 256 (1-D): b = bid&7 -> all blocks
// of batch b land on XCD b (round-robin dispatch): Q_b + K_b = 1 MB is
// L2-resident. 64-col strips, 4 waves, wave owns 16 cols (1 ct); every wave
// sweeps ALL 2048 rows -> colsums are FINAL (no partials, no cross-block
// comm). Writes cs into pi head (stream-ordered alias) and y directly.
// ---------------------------------------------------------------------------
__global__ __launch_bounds__(256) void colsum_kernel(
    const u16* __restrict__ Qs, const u16* __restrict__ Ks,
    const float* __restrict__ x, float* __restrict__ y,
    float* __restrict__ csbuf)
{
    __shared__ float xs[NN * 3];             // 24 KB

    const int tid   = threadIdx.x;
    const int bid   = blockIdx.x;
    const int b     = bid & 7;               // XCD affinity
    const int strip = bid >> 3;              // 0..31
    const int m0    = strip * 64;
    const int wave  = tid >> 6;              // 0..3
    const int lane  = tid & 63;
    const int l15   = lane & 15;
    const int quad  = lane >> 4;

    for (int i = tid; i < NN * 3; i += 256) xs[i] = x[(size_t)b * NN * 3 + i];
    __syncthreads();

    // this wave's 16-col K fragment (resident)
    bf16x8 bh[2], bl[2];
    {
        const u16* kr = Ks + ((size_t)b * NN + m0 + wave * 16 + l15) * 128;
#pragma unroll
        for (int ks = 0; ks < 2; ++ks) {
            int k0 = ks * 32 + quad * 8;
            bh[ks] = *(const bf16x8*)(kr + k0);
            bl[ks] = *(const bf16x8*)(kr + 64 + k0);
        }
    }

    const u16* Qb = Qs + (size_t)b * NN * 128;
    float cs = 0.f, yac0 = 0.f, yac1 = 0.f, yac2 = 0.f;

#define CSBODY(ROW0, AH, AL)                                                   \
    {                                                                          \
        f32x4 acc = {0.f, 0.f, 0.f, 0.f};                                      \
        _Pragma("unroll")                                                      \
        for (int ks = 0; ks < 2; ++ks) {                                       \
            acc = __builtin_amdgcn_mfma_f32_16x16x32_bf16(AH[ks], bh[ks], acc, 0, 0, 0); \
            acc = __builtin_amdgcn_mfma_f32_16x16x32_bf16(AH[ks], bl[ks], acc, 0, 0, 0); \
            acc = __builtin_amdgcn_mfma_f32_16x16x32_bf16(AL[ks], bh[ks], acc, 0, 0, 0); \
        }                                                                      \
        _Pragma("unroll")                                                      \
        for (int r = 0; r < 4; ++r) {                                          \
            float v = __expf(acc[r]);                                          \
            int row = (ROW0) + quad * 4 + r;                                   \
            cs += v;                                                           \
            yac0 = fmaf(v, xs[row * 3 + 0], yac0);                             \
            yac1 = fmaf(v, xs[row * 3 + 1], yac1);                             \
            yac2 = fmaf(v, xs[row * 3 + 2], yac2);                             \
        }                                                                      \
    }

    {
        bf16x8 ahA[2], alA[2], ahB[2], alB[2];
        LOADQF(ahA, alA, 0);
        for (int it = 0; it < 128; it += 2) {
            LOADQF(ahB, alB, (it + 1) * 16);
            CSBODY(it * 16, ahA, alA);
            if (it + 2 < 128) LOADQF(ahA, alA, (it + 2) * 16);
            CSBODY((it + 1) * 16, ahB, alB);
        }
    }
#undef CSBODY

    // reduce over quads (same col lives at same l15 in all quads)
    cs   += __shfl_xor(cs, 16);   cs   += __shfl_xor(cs, 32);
    yac0 += __shfl_xor(yac0, 16); yac0 += __shfl_xor(yac0, 32);
    yac1 += __shfl_xor(yac1, 16); yac1 += __shfl_xor(yac1, 32);
    yac2 += __shfl_xor(yac2, 16); yac2 += __shfl_xor(yac2, 32);

    if (quad == 0) {
        const int col = m0 + wave * 16 + l15;
        csbuf[(size_t)b * NN + col] = cs;
        float inv = 1.0f / cs;
        float* yp = y + ((size_t)b * NN + col) * 3;
        yp[0] = yac0 * inv;
        yp[1] = yac1 * inv;
        yp[2] = yac2 * inv;
    }
}

// ---------------------------------------------------------------------------
// Kernel 3: pi writer. Grid 1024: b = bid&7 (XCD affinity), 256-row x
// 128-col tiles, 4 waves x 32 cols (2 ct). Reads cs from pi head; NEVER
// writes the cs region (b0 rows 0-7 skipped -> race-free by construction;
// cleanup_kernel fills them afterwards).
// ---------------------------------------------------------------------------
__global__ __launch_bounds__(256, 4) void pi_kernel(
    const u16* __restrict__ Qs, const u16* __restrict__ Ks,
    const float* __restrict__ csbuf, float* __restrict__ pi)
{
    const int tid   = threadIdx.x;
    const int bid   = blockIdx.x;
    const int b     = bid & 7;               // XCD affinity
    const int t     = bid >> 3;              // 0..127
    const int rc    = t & 7;                 // row chunk (256 rows)
    const int strip = t >> 3;                // 0..15  (128 cols)
    const int m0    = strip * 128;
    const int wave  = tid >> 6;              // 0..3
    const int lane  = tid & 63;
    const int l15   = lane & 15;
    const int quad  = lane >> 4;

    const int c0 = m0 + wave * 32 + l15;     // ct=0 col
    const int c1 = c0 + 16;                  // ct=1 col
    const float invN = 1.0f / (float)NN;
    const float iv0 = invN / csbuf[(size_t)b * NN + c0];
    const float iv1 = invN / csbuf[(size_t)b * NN + c1];

    // K fragments for 2 col-tiles (resident)
    bf16x8 bh[2][2], bl[2][2];
#pragma unroll
    for (int ct = 0; ct < 2; ++ct) {
        const u16* kr = Ks + ((size_t)b * NN + m0 + wave * 32 + ct * 16 + l15) * 128;
#pragma unroll
        for (int ks = 0; ks < 2; ++ks) {
            int k0 = ks * 32 + quad * 8;
            bh[ct][ks] = *(const bf16x8*)(kr + k0);
            bl[ct][ks] = *(const bf16x8*)(kr + 64 + k0);
        }
    }

    const u16* Qb = Qs + (size_t)b * NN * 128;
    const int row_base = rc * 256;
    // skip-store rows 0-7 of b0 (the cs region): only first iter of (b0,rc0)
    const bool guard0 = (b == 0) && (rc == 0);

#define PIBODY(IT, AH, AL)                                                     \
    {                                                                          \
        const int row0 = row_base + (IT) * 16;                                 \
        const bool full = !(guard0 && (IT) == 0);                              \
        _Pragma("unroll")                                                      \
        for (int ct = 0; ct < 2; ++ct) {                                       \
            f32x4 acc = {0.f, 0.f, 0.f, 0.f};                                  \
            _Pragma("unroll")                                                  \
            for (int ks = 0; ks < 2; ++ks) {                                   \
                acc = __builtin_amdgcn_mfma_f32_16x16x32_bf16(AH[ks], bh[ct][ks], acc, 0, 0, 0); \
                acc = __builtin_amdgcn_mfma_f32_16x16x32_bf16(AH[ks], bl[ct][ks], acc, 0, 0, 0); \
                acc = __builtin_amdgcn_mfma_f32_16x16x32_bf16(AL[ks], bh[ct][ks], acc, 0, 0, 0); \
            }                                                                  \
            const float iv = (ct == 0) ? iv0 : iv1;                            \
            const int cc   = (ct == 0) ? c0 : c1;                              \
            float* op = pi + ((size_t)b * NN + row0 + quad * 4) * NN + cc;     \
            if (full || quad >= 2) {                                           \
                _Pragma("unroll")                                              \
                for (int r = 0; r < 4; ++r)                                    \
                    op[(size_t)r * NN] = __expf(acc[r]) * iv;                  \
            }                                                                  \
        }                                                                      \
    }

    {
        bf16x8 ahA[2], alA[2], ahB[2], alB[2];
        LOADQF(ahA, alA, row_base);
        for (int it = 0; it < 16; it += 2) {
            LOADQF(ahB, alB, row_base + (it + 1) * 16);
            PIBODY(it, ahA, alA);
            if (it + 2 < 16) LOADQF(ahA, alA, row_base + (it + 2) * 16);
            PIBODY(it + 1, ahB, alB);
        }
    }
#undef PIBODY
}

// ---------------------------------------------------------------------------
// Kernel 4: cleanup — fill pi(b=0, rows 0-7, all cols), which held cs during
// pi_kernel. Each block owns a 256-col slice; stages its cs slice + Q rows
// 0-7 in LDS BEFORE overwriting (single-block read-then-write, race-free).
// Uses full split-bf16 reconstruction (more accurate than the MFMA path).
// ---------------------------------------------------------------------------
__global__ __launch_bounds__(512) void cleanup_kernel(
    const u16* __restrict__ Qs, const u16* __restrict__ Ks,
    float* __restrict__ pi)
{
    __shared__ float csl[256];
    __shared__ u16 ql[8 * 128];

    const int s   = blockIdx.x;              // 0..7: cols s*256..
    const int tid = threadIdx.x;

    if (tid < 256) csl[tid] = pi[s * 256 + tid];   // cs[b0][own cols]
    for (int i = tid; i < 1024; i += 512) ql[i] = Qs[i]; // b0 rows 0-7
    __syncthreads();

    const float invN = 1.0f / (float)NN;
#pragma unroll
    for (int k = 0; k < 4; ++k) {
        const int idx = tid + k * 512;       // 0..2047
        const int row = idx >> 8;            // 0..7
        const int cl  = idx & 255;
        const int col = s * 256 + cl;
        const u16* kk = Ks + (size_t)col * 128;      // b = 0
        float dot = 0.f;
#pragma unroll 8
        for (int h = 0; h < 64; ++h) {
            float qf = bfbits2f(ql[row * 128 + h]) + bfbits2f(ql[row * 128 + 64 + h]);
            float kf = bfbits2f(kk[h]) + bfbits2f(kk[64 + h]);
            dot = fmaf(qf, kf, dot);
        }
        pi[(size_t)row * NN + col] = __expf(dot) * invN / csl[cl];
    }
}

// ---------------------------------------------------------------------------
extern "C" void kernel_launch(void* const* d_in, const int* in_sizes, int n_in,
                              void* d_out, int out_size, void* d_ws, size_t ws_size,
                              hipStream_t stream) {
    const float* f  = (const float*)d_in[0];
    const float* x  = (const float*)d_in[1];
    const float* le = (const float*)d_in[2];
    const float* Wq = (const float*)d_in[3];
    const float* Wk = (const float*)d_in[4];

    float* y  = (float*)d_out;                       // (B, N, 3)
    float* pi = (float*)d_out + (size_t)BB * NN * 3; // (B, N, N)

    // Workspace: exactly the proven 8 MB (split-bf16 Q and K). All scratch
    // aliases the pi head with stream-ordered lifetimes:
    //   wprep -> Wsp (128 KB, rows 0-15 of b0) -> consumed by qk
    //   colsum -> cs (64 KB, rows 0-7 of b0)  -> consumed by pi_kernel,
    //   overwritten last by cleanup_kernel.
    __hip_bfloat16* Qs = (__hip_bfloat16*)d_ws;      // 4 MB
    __hip_bfloat16* Ks = Qs + (size_t)BB * NN * 128; // 4 MB
    u16*   Wsp   = (u16*)pi;
    float* csbuf = pi;

    wprep_kernel<<<dim3(64), 64, 0, stream>>>(Wq, Wk, Wsp);
    qk_mfma_kernel<<<dim3(BB * NN / 64), 256, 0, stream>>>(f, le, Wq, Wk, Wsp, Qs, Ks);
    colsum_kernel<<<dim3(256), 256, 0, stream>>>((const u16*)Qs, (const u16*)Ks,
                                                 x, y, csbuf);
    pi_kernel<<<dim3(1024), 256, 0, stream>>>((const u16*)Qs, (const u16*)Ks,
                                              csbuf, pi);
    cleanup_kernel<<<dim3(8), 512, 0, stream>>>((const u16*)Qs, (const u16*)Ks, pi);
}